// Round 1
// baseline (638.758 us; speedup 1.0000x reference)
//
#include <hip/hip_runtime.h>
#include <math.h>

#define Bsz 8
#define C 512
#define HW 4096
#define N 1024
#define NPIX (Bsz*HW)   // 32768

// ---------- K0: row norms of centers (->cnorm) and clusters (->clnorm) ----------
__global__ __launch_bounds__(64) void k_norms(const float* __restrict__ centers,
                                              const float* __restrict__ clusters,
                                              float* __restrict__ cnorm,
                                              float* __restrict__ clnorm) {
    int r = blockIdx.x;
    const float* src = (r < N) ? (centers + (size_t)r * C) : (clusters + (size_t)(r - N) * C);
    int lane = threadIdx.x;
    float s = 0.f;
    for (int k = lane; k < C; k += 64) { float v = src[k]; s += v * v; }
    #pragma unroll
    for (int m = 1; m < 64; m <<= 1) s += __shfl_xor(s, m, 64);
    if (lane == 0) {
        float nrm = sqrtf(s);
        if (nrm < 1e-12f) nrm = 1e-12f;   // F.normalize eps guard
        if (r < N) cnorm[r] = nrm; else clnorm[r - N] = nrm;
    }
}

// ---------- K1: M[i][j] = dot(centers[i],clusters[j]) / (cnorm[i]*clnorm[j]) ----------
__global__ __launch_bounds__(256) void k_gemmM(const float* __restrict__ centers,
                                               const float* __restrict__ clusters,
                                               const float* __restrict__ cnorm,
                                               const float* __restrict__ clnorm,
                                               float* __restrict__ M) {
    __shared__ float as[32][68];   // k-major, padded
    __shared__ float bs[32][68];
    int tid = threadIdx.x;
    int tx = tid & 15, ty = tid >> 4;
    int i0 = blockIdx.x * 64, j0 = blockIdx.y * 64;
    int lrow = tid >> 2, lkq = (tid & 3) * 8;
    float acc[4][4] = {};
    for (int kc = 0; kc < C; kc += 32) {
        float4 a0 = *(const float4*)(centers + (size_t)(i0 + lrow) * C + kc + lkq);
        float4 a1 = *(const float4*)(centers + (size_t)(i0 + lrow) * C + kc + lkq + 4);
        float4 b0 = *(const float4*)(clusters + (size_t)(j0 + lrow) * C + kc + lkq);
        float4 b1 = *(const float4*)(clusters + (size_t)(j0 + lrow) * C + kc + lkq + 4);
        __syncthreads();   // previous iteration's reads complete
        as[lkq+0][lrow]=a0.x; as[lkq+1][lrow]=a0.y; as[lkq+2][lrow]=a0.z; as[lkq+3][lrow]=a0.w;
        as[lkq+4][lrow]=a1.x; as[lkq+5][lrow]=a1.y; as[lkq+6][lrow]=a1.z; as[lkq+7][lrow]=a1.w;
        bs[lkq+0][lrow]=b0.x; bs[lkq+1][lrow]=b0.y; bs[lkq+2][lrow]=b0.z; bs[lkq+3][lrow]=b0.w;
        bs[lkq+4][lrow]=b1.x; bs[lkq+5][lrow]=b1.y; bs[lkq+6][lrow]=b1.z; bs[lkq+7][lrow]=b1.w;
        __syncthreads();
        #pragma unroll
        for (int k = 0; k < 32; k += 4) {
            float av[4][4], bv[4][4];
            #pragma unroll
            for (int kk = 0; kk < 4; ++kk) {
                float4 ta = *(const float4*)&as[k+kk][tx*4];
                float4 tb = *(const float4*)&bs[k+kk][ty*4];
                av[kk][0]=ta.x; av[kk][1]=ta.y; av[kk][2]=ta.z; av[kk][3]=ta.w;
                bv[kk][0]=tb.x; bv[kk][1]=tb.y; bv[kk][2]=tb.z; bv[kk][3]=tb.w;
            }
            #pragma unroll
            for (int kk = 0; kk < 4; ++kk)
                #pragma unroll
                for (int ii = 0; ii < 4; ++ii)
                    #pragma unroll
                    for (int jj = 0; jj < 4; ++jj)
                        acc[ii][jj] = fmaf(av[kk][ii], bv[kk][jj], acc[ii][jj]);
        }
    }
    float rci[4], rcj[4];
    #pragma unroll
    for (int ii = 0; ii < 4; ++ii) rci[ii] = cnorm[i0 + tx*4 + ii];
    #pragma unroll
    for (int jj = 0; jj < 4; ++jj) rcj[jj] = clnorm[j0 + ty*4 + jj];
    #pragma unroll
    for (int ii = 0; ii < 4; ++ii)
        #pragma unroll
        for (int jj = 0; jj < 4; ++jj)
            M[(size_t)(i0 + tx*4 + ii) * N + (j0 + ty*4 + jj)] = acc[ii][jj] / (rci[ii] * rcj[jj]);
}

// ---------- K2: per-row max + argmax (first-index tie-break) of M ----------
__global__ __launch_bounds__(256) void k_rowstat(const float* __restrict__ M,
                                                 float* __restrict__ rowmax,
                                                 int* __restrict__ rowarg) {
    __shared__ float sv[256];
    __shared__ int   sa[256];
    int i = blockIdx.x, tid = threadIdx.x;
    float bv = -INFINITY; int ba = 0;
    for (int j = tid; j < N; j += 256) {
        float v = M[(size_t)i * N + j];
        if (v > bv || (v == bv && j < ba)) { bv = v; ba = j; }
    }
    sv[tid] = bv; sa[tid] = ba;
    __syncthreads();
    for (int s = 128; s > 0; s >>= 1) {
        if (tid < s) {
            float v = sv[tid + s]; int a = sa[tid + s];
            if (v > sv[tid] || (v == sv[tid] && a < sa[tid])) { sv[tid] = v; sa[tid] = a; }
        }
        __syncthreads();
    }
    if (tid == 0) { rowmax[i] = sv[0]; rowarg[i] = sa[0]; }
}

// ---------- K3: big argmax GEMM: idx[p] = argmax_n (x[p]·centers[n] + gumbel[p,n]) ----------
__global__ __launch_bounds__(512) void k_argmax(const float* __restrict__ x,
                                                const float* __restrict__ centers,
                                                const float* __restrict__ gumbel,
                                                int* __restrict__ idxout) {
    __shared__ float xs[C * 64];   // 128 KiB: x-tile [k][pixel], k-major
    int tid = threadIdx.x;
    int tx = tid & 15;             // pixel quad
    int ty = tid >> 4;             // 0..31: n group
    int b = blockIdx.x >> 6;
    int hw0 = (blockIdx.x & 63) << 6;
    const float* xb = x + (size_t)b * C * HW + hw0;
    for (int k = ty; k < C; k += 32) {
        float4 v = *(const float4*)(xb + (size_t)k * HW + tx * 4);
        *(float4*)&xs[k * 64 + tx * 4] = v;
    }
    __syncthreads();
    float best[4] = {-INFINITY, -INFINITY, -INFINITY, -INFINITY};
    int bestn[4] = {0, 0, 0, 0};
    for (int c = 0; c < 4; ++c) {              // 4 chunks x 256 n
        int nb = c * 256 + ty * 8;
        const float* cen = centers + (size_t)nb * C;
        float acca[4][8] = {};
        float accb[4][8] = {};
        for (int k = 0; k < C; k += 4) {
            float xv[4][4];
            #pragma unroll
            for (int kk = 0; kk < 4; ++kk) {
                float4 t = *(const float4*)&xs[(k + kk) * 64 + tx * 4];
                xv[kk][0]=t.x; xv[kk][1]=t.y; xv[kk][2]=t.z; xv[kk][3]=t.w;
            }
            #pragma unroll
            for (int j = 0; j < 8; ++j) {
                float4 cv = *(const float4*)(cen + (size_t)j * C + k);
                #pragma unroll
                for (int i = 0; i < 4; ++i) {
                    acca[i][j] = fmaf(xv[0][i], cv.x, acca[i][j]);
                    acca[i][j] = fmaf(xv[1][i], cv.y, acca[i][j]);
                    accb[i][j] = fmaf(xv[2][i], cv.z, accb[i][j]);
                    accb[i][j] = fmaf(xv[3][i], cv.w, accb[i][j]);
                }
            }
        }
        #pragma unroll
        for (int j = 0; j < 8; ++j) {
            int n = nb + j;
            float4 g = *(const float4*)(gumbel + ((size_t)b * N + n) * HW + hw0 + tx * 4);
            float gv[4] = {g.x, g.y, g.z, g.w};
            #pragma unroll
            for (int i = 0; i < 4; ++i) {
                float v = (acca[i][j] + accb[i][j]) + gv[i];
                if (v > best[i] || (v == best[i] && n < bestn[i])) { best[i] = v; bestn[i] = n; }
            }
        }
    }
    __syncthreads();   // done reading xs; reuse for reduction
    float* rv = xs;                    // [32][64]
    int*   rn = (int*)(xs + 32 * 64);  // [32][64]
    #pragma unroll
    for (int i = 0; i < 4; ++i) { rv[ty * 64 + tx * 4 + i] = best[i]; rn[ty * 64 + tx * 4 + i] = bestn[i]; }
    __syncthreads();
    if (tid < 64) {
        int p = tid;
        float bv = rv[p]; int bn = rn[p];
        for (int t = 1; t < 32; ++t) {
            float v = rv[t * 64 + p]; int n2 = rn[t * 64 + p];
            if (v > bv || (v == bv && n2 < bn)) { bv = v; bn = n2; }
        }
        idxout[blockIdx.x * 64 + p] = bn;
    }
}

// ---------- K4: gather rows of src by idx and write transposed (coalesced) ----------
// dst[((b*ncols + j)*HW) + hw] = src[idx[b*HW+hw]][j]
__global__ __launch_bounds__(256) void k_gather(const float* __restrict__ src, int ncols,
                                                const int* __restrict__ idx,
                                                float* __restrict__ dst) {
    __shared__ float rows[64][65];
    int tile = blockIdx.x;              // 512 pixel tiles of 64
    int col0 = blockIdx.y * 64;
    int tid = threadIdx.x;
    int lane = tid & 63, w = tid >> 6;  // 4 waves
    int b = tile >> 6, hw0 = (tile & 63) << 6;
    #pragma unroll
    for (int r8 = 0; r8 < 16; ++r8) {
        int r = w * 16 + r8;
        int row = idx[tile * 64 + r];
        rows[r][lane] = src[(size_t)row * ncols + col0 + lane];
    }
    __syncthreads();
    #pragma unroll
    for (int jj = 0; jj < 16; ++jj) {
        int j = col0 + w * 16 + jj;
        dst[((size_t)b * ncols + j) * HW + hw0 + lane] = rows[lane][w * 16 + jj];
    }
}

// ---------- K5: preds (as float) + per-block loss partial sums ----------
__global__ __launch_bounds__(256) void k_preds(const int* __restrict__ idx,
                                               const float* __restrict__ rowmax,
                                               const int* __restrict__ rowarg,
                                               float* __restrict__ preds_out,
                                               float* __restrict__ partial) {
    __shared__ float sv[256];
    int gid = blockIdx.x * 256 + threadIdx.x;
    int i = idx[gid];
    preds_out[gid] = (float)rowarg[i];
    sv[threadIdx.x] = rowmax[i];
    __syncthreads();
    for (int s = 128; s > 0; s >>= 1) {
        if (threadIdx.x < s) sv[threadIdx.x] += sv[threadIdx.x + s];
        __syncthreads();
    }
    if (threadIdx.x == 0) partial[blockIdx.x] = sv[0];
}

// ---------- K6: finalize loss ----------
__global__ __launch_bounds__(128) void k_loss(const float* __restrict__ partial,
                                              float* __restrict__ out) {
    __shared__ float sv[128];
    sv[threadIdx.x] = partial[threadIdx.x];
    __syncthreads();
    for (int s = 64; s > 0; s >>= 1) {
        if (threadIdx.x < s) sv[threadIdx.x] += sv[threadIdx.x + s];
        __syncthreads();
    }
    if (threadIdx.x == 0) out[0] = -(sv[0] / 32768.0f);
}

extern "C" void kernel_launch(void* const* d_in, const int* in_sizes, int n_in,
                              void* d_out, int out_size, void* d_ws, size_t ws_size,
                              hipStream_t stream) {
    const float* x        = (const float*)d_in[0];
    const float* centers  = (const float*)d_in[1];
    const float* clusters = (const float*)d_in[2];
    const float* gumbel   = (const float*)d_in[3];
    float* out = (float*)d_out;

    char* w = (char*)d_ws;
    int*   idxb    = (int*)w;                       // 32768 ints
    float* cnorm   = (float*)(w + 32768 * 4);       // 1024
    float* clnorm  = cnorm + 1024;                  // 1024
    float* rowmax  = clnorm + 1024;                 // 1024
    int*   rowarg  = (int*)(rowmax + 1024);         // 1024
    float* partial = (float*)(rowarg + 1024);       // 128
    float* M       = (float*)(w + 262144);          // 1024*1024 floats (4 MiB)

    float* out_loss  = out;
    float* out_preds = out + 1;
    float* out_ip    = out + 1 + 32768;
    float* out_zq    = out + 1 + 32768 + (size_t)N * NPIX;   // + 33554432

    k_norms  <<<2048, 64, 0, stream>>>(centers, clusters, cnorm, clnorm);
    k_gemmM  <<<dim3(16, 16), 256, 0, stream>>>(centers, clusters, cnorm, clnorm, M);
    k_rowstat<<<1024, 256, 0, stream>>>(M, rowmax, rowarg);
    k_argmax <<<512, 512, 0, stream>>>(x, centers, gumbel, idxb);
    k_gather <<<dim3(512, 16), 256, 0, stream>>>(M, N, idxb, out_ip);
    k_gather <<<dim3(512, 8),  256, 0, stream>>>(centers, C, idxb, out_zq);
    k_preds  <<<128, 256, 0, stream>>>(idxb, rowmax, rowarg, out_preds, partial);
    k_loss   <<<1, 128, 0, stream>>>(partial, out_loss);
}

// Round 2
// 359.188 us; speedup vs baseline: 1.7783x; 1.7783x over previous
//
#include <hip/hip_runtime.h>
#include <math.h>

#define C 512
#define HW 4096
#define N 1024
#define NPIX 32768
#define MARGIN 2.0f

typedef short s16x8 __attribute__((ext_vector_type(8)));
typedef float f32x4 __attribute__((ext_vector_type(4)));

__device__ inline unsigned short f2bf(float f) {
    unsigned int u = __float_as_uint(f);
    return (unsigned short)((u + 0x7FFFu + ((u >> 16) & 1u)) >> 16);
}
__device__ inline float h2f(unsigned short u) {
    _Float16 h; __builtin_memcpy(&h, &u, 2); return (float)h;
}
__device__ inline unsigned short f2h(float f) {
    _Float16 h = (_Float16)f; unsigned short u; __builtin_memcpy(&u, &h, 2); return u;
}
__device__ inline unsigned int mono(float v) {
    unsigned int u = __float_as_uint(v);
    return (u & 0x80000000u) ? ~u : (u | 0x80000000u);
}

// ---------- K0: row norms of centers (->cnorm) and clusters (->clnorm) ----------
__global__ __launch_bounds__(64) void k_norms(const float* __restrict__ centers,
                                              const float* __restrict__ clusters,
                                              float* __restrict__ cnorm,
                                              float* __restrict__ clnorm) {
    int r = blockIdx.x;
    const float* src = (r < N) ? (centers + (size_t)r * C) : (clusters + (size_t)(r - N) * C);
    int lane = threadIdx.x;
    float s = 0.f;
    for (int k = lane; k < C; k += 64) { float v = src[k]; s += v * v; }
    #pragma unroll
    for (int m = 1; m < 64; m <<= 1) s += __shfl_xor(s, m, 64);
    if (lane == 0) {
        float nrm = sqrtf(s);
        if (nrm < 1e-12f) nrm = 1e-12f;
        if (r < N) cnorm[r] = nrm; else clnorm[r - N] = nrm;
    }
}

// ---------- K1: M[i][j] = dot(centers[i],clusters[j]) / (cnorm[i]*clnorm[j]) ----------
__global__ __launch_bounds__(256) void k_gemmM(const float* __restrict__ centers,
                                               const float* __restrict__ clusters,
                                               const float* __restrict__ cnorm,
                                               const float* __restrict__ clnorm,
                                               float* __restrict__ M) {
    __shared__ float as[32][68];
    __shared__ float bs[32][68];
    int tid = threadIdx.x;
    int tx = tid & 15, ty = tid >> 4;
    int i0 = blockIdx.x * 64, j0 = blockIdx.y * 64;
    int lrow = tid >> 2, lkq = (tid & 3) * 8;
    float acc[4][4] = {};
    for (int kc = 0; kc < C; kc += 32) {
        float4 a0 = *(const float4*)(centers + (size_t)(i0 + lrow) * C + kc + lkq);
        float4 a1 = *(const float4*)(centers + (size_t)(i0 + lrow) * C + kc + lkq + 4);
        float4 b0 = *(const float4*)(clusters + (size_t)(j0 + lrow) * C + kc + lkq);
        float4 b1 = *(const float4*)(clusters + (size_t)(j0 + lrow) * C + kc + lkq + 4);
        __syncthreads();
        as[lkq+0][lrow]=a0.x; as[lkq+1][lrow]=a0.y; as[lkq+2][lrow]=a0.z; as[lkq+3][lrow]=a0.w;
        as[lkq+4][lrow]=a1.x; as[lkq+5][lrow]=a1.y; as[lkq+6][lrow]=a1.z; as[lkq+7][lrow]=a1.w;
        bs[lkq+0][lrow]=b0.x; bs[lkq+1][lrow]=b0.y; bs[lkq+2][lrow]=b0.z; bs[lkq+3][lrow]=b0.w;
        bs[lkq+4][lrow]=b1.x; bs[lkq+5][lrow]=b1.y; bs[lkq+6][lrow]=b1.z; bs[lkq+7][lrow]=b1.w;
        __syncthreads();
        #pragma unroll
        for (int k = 0; k < 32; k += 4) {
            float av[4][4], bv[4][4];
            #pragma unroll
            for (int kk = 0; kk < 4; ++kk) {
                float4 ta = *(const float4*)&as[k+kk][tx*4];
                float4 tb = *(const float4*)&bs[k+kk][ty*4];
                av[kk][0]=ta.x; av[kk][1]=ta.y; av[kk][2]=ta.z; av[kk][3]=ta.w;
                bv[kk][0]=tb.x; bv[kk][1]=tb.y; bv[kk][2]=tb.z; bv[kk][3]=tb.w;
            }
            #pragma unroll
            for (int kk = 0; kk < 4; ++kk)
                #pragma unroll
                for (int ii = 0; ii < 4; ++ii)
                    #pragma unroll
                    for (int jj = 0; jj < 4; ++jj)
                        acc[ii][jj] = fmaf(av[kk][ii], bv[kk][jj], acc[ii][jj]);
        }
    }
    float rci[4], rcj[4];
    #pragma unroll
    for (int ii = 0; ii < 4; ++ii) rci[ii] = cnorm[i0 + tx*4 + ii];
    #pragma unroll
    for (int jj = 0; jj < 4; ++jj) rcj[jj] = clnorm[j0 + ty*4 + jj];
    #pragma unroll
    for (int ii = 0; ii < 4; ++ii)
        #pragma unroll
        for (int jj = 0; jj < 4; ++jj)
            M[(size_t)(i0 + tx*4 + ii) * N + (j0 + ty*4 + jj)] = acc[ii][jj] / (rci[ii] * rcj[jj]);
}

// ---------- K2: per-row max + argmax (first-index tie-break) of M ----------
__global__ __launch_bounds__(256) void k_rowstat(const float* __restrict__ M,
                                                 float* __restrict__ rowmax,
                                                 int* __restrict__ rowarg) {
    __shared__ float sv[256];
    __shared__ int   sa[256];
    int i = blockIdx.x, tid = threadIdx.x;
    float bv = -INFINITY; int ba = 0;
    for (int j = tid; j < N; j += 256) {
        float v = M[(size_t)i * N + j];
        if (v > bv || (v == bv && j < ba)) { bv = v; ba = j; }
    }
    sv[tid] = bv; sa[tid] = ba;
    __syncthreads();
    for (int s = 128; s > 0; s >>= 1) {
        if (tid < s) {
            float v = sv[tid + s]; int a = sa[tid + s];
            if (v > sv[tid] || (v == sv[tid] && a < sa[tid])) { sv[tid] = v; sa[tid] = a; }
        }
        __syncthreads();
    }
    if (tid == 0) { rowmax[i] = sv[0]; rowarg[i] = sa[0]; }
}

// ---------- K3: transpose x[b][k][p] -> xT[b*4096+p][k] (fp32) ----------
__global__ __launch_bounds__(256) void k_prepT(const float* __restrict__ x,
                                               float* __restrict__ xT) {
    __shared__ float t[64][65];
    int bidx = blockIdx.x;              // 8 b * 8 ktile * 64 ptile
    int pt = bidx & 63, kt = (bidx >> 6) & 7, b = bidx >> 9;
    int r = threadIdx.x >> 4, c4 = (threadIdx.x & 15) * 4;
    const float* src = x + ((size_t)b * C + kt * 64) * HW + pt * 64;
    #pragma unroll
    for (int rr = 0; rr < 4; ++rr) {
        int row = rr * 16 + r;
        float4 v = *(const float4*)(src + (size_t)row * HW + c4);
        t[row][c4] = v.x; t[row][c4+1] = v.y; t[row][c4+2] = v.z; t[row][c4+3] = v.w;
    }
    __syncthreads();
    float* dst = xT + ((size_t)b * HW + pt * 64) * C + kt * 64;
    #pragma unroll
    for (int rr = 0; rr < 4; ++rr) {
        int row = rr * 16 + r;          // pixel within tile
        float4 v = { t[c4][row], t[c4+1][row], t[c4+2][row], t[c4+3][row] };
        *(float4*)(dst + (size_t)row * C + c4) = v;
    }
}

// ---------- K4: centers -> bf16 MFMA B-fragments (fragment-linear) ----------
__global__ __launch_bounds__(64) void k_cenfrag(const float* __restrict__ centers,
                                                unsigned short* __restrict__ cenB) {
    int f = blockIdx.x;                 // nt*16 + kt
    int nt = f >> 4, kt = f & 15;
    int lane = threadIdx.x;
    int r = lane & 15, g = lane >> 4;
    const float* src = centers + (size_t)(nt * 16 + r) * C + kt * 32 + g * 4;
    float4 lo = *(const float4*)src;
    float4 hi = *(const float4*)(src + 16);
    union { unsigned short us[8]; uint4 q; } u;
    u.us[0]=f2bf(lo.x); u.us[1]=f2bf(lo.y); u.us[2]=f2bf(lo.z); u.us[3]=f2bf(lo.w);
    u.us[4]=f2bf(hi.x); u.us[5]=f2bf(hi.y); u.us[6]=f2bf(hi.z); u.us[7]=f2bf(hi.w);
    *(uint4*)(cenB + ((size_t)f * 64 + lane) * 8) = u.q;
}

// ---------- K5: MFMA logits = x.centers + gumbel, stored fp16 [p][n] ----------
__global__ __launch_bounds__(256, 4) void k_mfma(const float* __restrict__ xT,
                                                 const unsigned short* __restrict__ cenB,
                                                 const float* __restrict__ gumbel,
                                                 unsigned short* __restrict__ logits) {
    int lane = threadIdx.x & 63;
    int gw = blockIdx.x * 4 + (threadIdx.x >> 6);   // 4096 waves
    int p0 = (gw >> 1) * 16;
    int half = gw & 1;
    int b = p0 >> 12, hw0 = p0 & (HW - 1);
    int r = lane & 15, g = lane >> 4;

    // A fragments: 16 px x 512 k, bf16, kept in registers
    s16x8 a[16];
    const float* xrow = xT + (size_t)(p0 + r) * C;
    #pragma unroll
    for (int kt = 0; kt < 16; ++kt) {
        float4 lo = *(const float4*)(xrow + kt * 32 + g * 4);
        float4 hi = *(const float4*)(xrow + kt * 32 + 16 + g * 4);
        s16x8 t;
        t[0] = (short)f2bf(lo.x); t[1] = (short)f2bf(lo.y);
        t[2] = (short)f2bf(lo.z); t[3] = (short)f2bf(lo.w);
        t[4] = (short)f2bf(hi.x); t[5] = (short)f2bf(hi.y);
        t[6] = (short)f2bf(hi.z); t[7] = (short)f2bf(hi.w);
        a[kt] = t;
    }
    const float* grow = gumbel + ((size_t)b * N + r) * HW + hw0 + g * 4;
    int nt0 = half * 32, nt1 = nt0 + 32;
    float4 gv = *(const float4*)(grow + (size_t)nt0 * 16 * HW);
    for (int nt = nt0; nt < nt1; ++nt) {
        float4 gvn = gv;
        if (nt + 1 < nt1) gvn = *(const float4*)(grow + (size_t)(nt + 1) * 16 * HW);
        f32x4 acc = {0.f, 0.f, 0.f, 0.f};
        #pragma unroll
        for (int kt = 0; kt < 16; ++kt) {
            s16x8 bf = *(const s16x8*)(cenB + ((size_t)(nt * 16 + kt) * 64 + lane) * 8);
            acc = __builtin_amdgcn_mfma_f32_16x16x32_bf16(a[kt], bf, acc, 0, 0, 0);
        }
        // D: col(n) = lane&15, row(pixel) = (lane>>4)*4 + reg
        unsigned short* lp = logits + (size_t)(p0 + g * 4) * N + nt * 16 + r;
        float gvv[4] = {gv.x, gv.y, gv.z, gv.w};
        #pragma unroll
        for (int j = 0; j < 4; ++j) lp[(size_t)j * N] = f2h(acc[j] + gvv[j]);
        gv = gvn;
    }
}

// ---------- K6: per-pixel max + candidates within MARGIN ----------
__global__ __launch_bounds__(256) void k_scan(const unsigned short* __restrict__ logits,
                                              unsigned int* __restrict__ ccount,
                                              unsigned int* __restrict__ cand) {
    int lane = threadIdx.x & 63;
    int p = blockIdx.x * 4 + (threadIdx.x >> 6);
    const unsigned short* row = logits + (size_t)p * N;
    uint4 q0 = *(const uint4*)(row + lane * 8);
    uint4 q1 = *(const uint4*)(row + 512 + lane * 8);
    unsigned int qa[8] = {q0.x, q0.y, q0.z, q0.w, q1.x, q1.y, q1.z, q1.w};
    float v[16];
    #pragma unroll
    for (int e = 0; e < 8; ++e) {
        v[e * 2]     = h2f((unsigned short)(qa[e] & 0xFFFFu));
        v[e * 2 + 1] = h2f((unsigned short)(qa[e] >> 16));
    }
    float m = v[0];
    #pragma unroll
    for (int j = 1; j < 16; ++j) m = fmaxf(m, v[j]);
    #pragma unroll
    for (int s = 1; s < 64; s <<= 1) m = fmaxf(m, __shfl_xor(m, s, 64));
    float thr = m - MARGIN;
    unsigned long long ltmask = ((unsigned long long)1 << lane) - 1ull;
    unsigned int total = 0;
    #pragma unroll
    for (int j = 0; j < 16; ++j) {
        bool c = v[j] >= thr;
        unsigned long long bal = __ballot(c);
        if (c) {
            unsigned int pos = total + (unsigned int)__popcll(bal & ltmask);
            if (pos < 32u) {
                int n = (j < 8) ? (lane * 8 + j) : (512 + lane * 8 + (j - 8));
                cand[(size_t)p * 32 + pos] = (unsigned int)n;
            }
        }
        total += (unsigned int)__popcll(bal);
    }
    if (lane == 0) ccount[p] = total < 32u ? total : 32u;
}

// ---------- K7: exact fp32 refinement of candidates -> pixbest key ----------
__global__ __launch_bounds__(256) void k_refine(const float* __restrict__ xT,
                                                const float* __restrict__ centers,
                                                const float* __restrict__ gumbel,
                                                const unsigned int* __restrict__ ccount,
                                                const unsigned int* __restrict__ cand,
                                                unsigned long long* __restrict__ pixbest) {
    int lane = threadIdx.x & 63;
    int gw = blockIdx.x * 4 + (threadIdx.x >> 6);    // 2048 waves
    for (int p = gw; p < NPIX; p += 2048) {
        int b = p >> 12, hw = p & (HW - 1);
        int cc = (int)ccount[p];
        const float* xr = xT + (size_t)p * C + lane * 8;
        float4 x0 = *(const float4*)xr;
        float4 x1 = *(const float4*)(xr + 4);
        unsigned long long bestkey = 0;
        for (int t = 0; t < cc; ++t) {
            int n = (int)cand[(size_t)p * 32 + t];
            float gval = gumbel[((size_t)b * N + n) * HW + hw];
            const float* cr = centers + (size_t)n * C + lane * 8;
            float4 c0 = *(const float4*)cr;
            float4 c1 = *(const float4*)(cr + 4);
            float s = 0.f;
            s = fmaf(x0.x, c0.x, s); s = fmaf(x0.y, c0.y, s);
            s = fmaf(x0.z, c0.z, s); s = fmaf(x0.w, c0.w, s);
            s = fmaf(x1.x, c1.x, s); s = fmaf(x1.y, c1.y, s);
            s = fmaf(x1.z, c1.z, s); s = fmaf(x1.w, c1.w, s);
            #pragma unroll
            for (int m2 = 1; m2 < 64; m2 <<= 1) s += __shfl_xor(s, m2, 64);
            float val = s + gval;
            unsigned long long key = ((unsigned long long)mono(val) << 32) | (unsigned int)(1023 - n);
            if (key > bestkey) bestkey = key;
        }
        if (lane == 0) pixbest[p] = bestkey;
    }
}

// ---------- K8: idx, preds (as float) + per-block loss partial sums ----------
__global__ __launch_bounds__(256) void k_preds(const unsigned long long* __restrict__ pixbest,
                                               const float* __restrict__ rowmax,
                                               const int* __restrict__ rowarg,
                                               int* __restrict__ idxb,
                                               float* __restrict__ preds_out,
                                               float* __restrict__ partial) {
    __shared__ float sv[256];
    int gid = blockIdx.x * 256 + threadIdx.x;
    unsigned long long key = pixbest[gid];
    int i = 1023 - (int)(unsigned int)(key & 0xFFFFFFFFull);
    idxb[gid] = i;
    preds_out[gid] = (float)rowarg[i];
    sv[threadIdx.x] = rowmax[i];
    __syncthreads();
    for (int s = 128; s > 0; s >>= 1) {
        if (threadIdx.x < s) sv[threadIdx.x] += sv[threadIdx.x + s];
        __syncthreads();
    }
    if (threadIdx.x == 0) partial[blockIdx.x] = sv[0];
}

// ---------- K9: gather rows of src by idx and write transposed (coalesced) ----------
__global__ __launch_bounds__(256) void k_gather(const float* __restrict__ src, int ncols,
                                                const int* __restrict__ idx,
                                                float* __restrict__ dst) {
    __shared__ float rows[64][65];
    int tile = blockIdx.x;
    int col0 = blockIdx.y * 64;
    int tid = threadIdx.x;
    int lane = tid & 63, w = tid >> 6;
    int b = tile >> 6, hw0 = (tile & 63) << 6;
    #pragma unroll
    for (int r8 = 0; r8 < 16; ++r8) {
        int r = w * 16 + r8;
        int row = idx[tile * 64 + r];
        rows[r][lane] = src[(size_t)row * ncols + col0 + lane];
    }
    __syncthreads();
    #pragma unroll
    for (int jj = 0; jj < 16; ++jj) {
        int j = col0 + w * 16 + jj;
        dst[((size_t)b * ncols + j) * HW + hw0 + lane] = rows[lane][w * 16 + jj];
    }
}

// ---------- K10: finalize loss ----------
__global__ __launch_bounds__(128) void k_loss(const float* __restrict__ partial,
                                              float* __restrict__ out) {
    __shared__ float sv[128];
    sv[threadIdx.x] = partial[threadIdx.x];
    __syncthreads();
    for (int s = 64; s > 0; s >>= 1) {
        if (threadIdx.x < s) sv[threadIdx.x] += sv[threadIdx.x + s];
        __syncthreads();
    }
    if (threadIdx.x == 0) out[0] = -(sv[0] / 32768.0f);
}

extern "C" void kernel_launch(void* const* d_in, const int* in_sizes, int n_in,
                              void* d_out, int out_size, void* d_ws, size_t ws_size,
                              hipStream_t stream) {
    const float* x        = (const float*)d_in[0];
    const float* centers  = (const float*)d_in[1];
    const float* clusters = (const float*)d_in[2];
    const float* gumbel   = (const float*)d_in[3];
    float* out = (float*)d_out;

    char* w = (char*)d_ws;
    int*   idxb    = (int*)w;                                  // 128 KB
    float* cnorm   = (float*)(w + 131072);                     // 4 KB
    float* clnorm  = cnorm + 1024;
    float* rowmax  = clnorm + 1024;
    int*   rowarg  = (int*)(rowmax + 1024);
    float* partial = (float*)(rowarg + 1024);
    float* M       = (float*)(w + 262144);                     // 4 MB
    unsigned int* ccount = (unsigned int*)(w + 4718592);       // 128 KB
    unsigned int* cand   = (unsigned int*)(w + 4849664);       // 4 MB
    unsigned short* cenB = (unsigned short*)(w + 9043968);     // 2 MB
    unsigned long long* pixbest = (unsigned long long*)(w + 11141120); // 256 KB

    float* out_loss  = out;
    float* out_preds = out + 1;
    float* out_ip    = out + 1 + 32768;
    float* out_zq    = out + 1 + 32768 + (size_t)N * NPIX;

    // scratch carved out of d_out (16B-aligned), dead before the final gathers:
    unsigned short* logits = (unsigned short*)(out + 40960);   // 67 MB fp16, inside out_ip
    float*          xT     = out + 16818176;                   // 67 MB fp32, ip/zq tail

    k_norms  <<<2048, 64, 0, stream>>>(centers, clusters, cnorm, clnorm);
    k_gemmM  <<<dim3(16, 16), 256, 0, stream>>>(centers, clusters, cnorm, clnorm, M);
    k_rowstat<<<1024, 256, 0, stream>>>(M, rowmax, rowarg);
    k_prepT  <<<4096, 256, 0, stream>>>(x, xT);
    k_cenfrag<<<1024, 64, 0, stream>>>(centers, cenB);
    k_mfma   <<<1024, 256, 0, stream>>>(xT, cenB, gumbel, logits);
    k_scan   <<<8192, 256, 0, stream>>>(logits, ccount, cand);
    k_refine <<<512, 256, 0, stream>>>(xT, centers, gumbel, ccount, cand, pixbest);
    k_preds  <<<128, 256, 0, stream>>>(pixbest, rowmax, rowarg, idxb, out_preds, partial);
    k_gather <<<dim3(512, 16), 256, 0, stream>>>(M, N, idxb, out_ip);
    k_gather <<<dim3(512, 8),  256, 0, stream>>>(centers, C, idxb, out_zq);
    k_loss   <<<1, 128, 0, stream>>>(partial, out_loss);
}

// Round 3
// 279.184 us; speedup vs baseline: 2.2879x; 1.2866x over previous
//
#include <hip/hip_runtime.h>
#include <math.h>

#define C 512
#define HW 4096
#define N 1024
#define NPIX 32768
#define MARGIN 2.0f
#define CAP 512

typedef short s16x8 __attribute__((ext_vector_type(8)));
typedef float f32x4 __attribute__((ext_vector_type(4)));

__device__ inline unsigned short f2bf(float f) {
    unsigned int u = __float_as_uint(f);
    return (unsigned short)((u + 0x7FFFu + ((u >> 16) & 1u)) >> 16);
}
__device__ inline unsigned int mono(float v) {
    unsigned int u = __float_as_uint(v);
    return (u & 0x80000000u) ? ~u : (u | 0x80000000u);
}
__device__ inline float unmono(unsigned int u) {
    unsigned int v = (u & 0x80000000u) ? (u & 0x7FFFFFFFu) : ~u;
    return __uint_as_float(v);
}

// ---------- K0: row norms of centers (->cnorm) and clusters (->clnorm) ----------
__global__ __launch_bounds__(64) void k_norms(const float* __restrict__ centers,
                                              const float* __restrict__ clusters,
                                              float* __restrict__ cnorm,
                                              float* __restrict__ clnorm) {
    int r = blockIdx.x;
    const float* src = (r < N) ? (centers + (size_t)r * C) : (clusters + (size_t)(r - N) * C);
    int lane = threadIdx.x;
    float s = 0.f;
    for (int k = lane; k < C; k += 64) { float v = src[k]; s += v * v; }
    #pragma unroll
    for (int m = 1; m < 64; m <<= 1) s += __shfl_xor(s, m, 64);
    if (lane == 0) {
        float nrm = sqrtf(s);
        if (nrm < 1e-12f) nrm = 1e-12f;
        if (r < N) cnorm[r] = nrm; else clnorm[r - N] = nrm;
    }
}

// ---------- K1: M[i][j] = dot(centers[i],clusters[j]) / (cnorm[i]*clnorm[j]) ----------
__global__ __launch_bounds__(256) void k_gemmM(const float* __restrict__ centers,
                                               const float* __restrict__ clusters,
                                               const float* __restrict__ cnorm,
                                               const float* __restrict__ clnorm,
                                               float* __restrict__ M) {
    __shared__ float as[32][68];
    __shared__ float bs[32][68];
    int tid = threadIdx.x;
    int tx = tid & 15, ty = tid >> 4;
    int i0 = blockIdx.x * 64, j0 = blockIdx.y * 64;
    int lrow = tid >> 2, lkq = (tid & 3) * 8;
    float acc[4][4] = {};
    for (int kc = 0; kc < C; kc += 32) {
        float4 a0 = *(const float4*)(centers + (size_t)(i0 + lrow) * C + kc + lkq);
        float4 a1 = *(const float4*)(centers + (size_t)(i0 + lrow) * C + kc + lkq + 4);
        float4 b0 = *(const float4*)(clusters + (size_t)(j0 + lrow) * C + kc + lkq);
        float4 b1 = *(const float4*)(clusters + (size_t)(j0 + lrow) * C + kc + lkq + 4);
        __syncthreads();
        as[lkq+0][lrow]=a0.x; as[lkq+1][lrow]=a0.y; as[lkq+2][lrow]=a0.z; as[lkq+3][lrow]=a0.w;
        as[lkq+4][lrow]=a1.x; as[lkq+5][lrow]=a1.y; as[lkq+6][lrow]=a1.z; as[lkq+7][lrow]=a1.w;
        bs[lkq+0][lrow]=b0.x; bs[lkq+1][lrow]=b0.y; bs[lkq+2][lrow]=b0.z; bs[lkq+3][lrow]=b0.w;
        bs[lkq+4][lrow]=b1.x; bs[lkq+5][lrow]=b1.y; bs[lkq+6][lrow]=b1.z; bs[lkq+7][lrow]=b1.w;
        __syncthreads();
        #pragma unroll
        for (int k = 0; k < 32; k += 4) {
            float av[4][4], bv[4][4];
            #pragma unroll
            for (int kk = 0; kk < 4; ++kk) {
                float4 ta = *(const float4*)&as[k+kk][tx*4];
                float4 tb = *(const float4*)&bs[k+kk][ty*4];
                av[kk][0]=ta.x; av[kk][1]=ta.y; av[kk][2]=ta.z; av[kk][3]=ta.w;
                bv[kk][0]=tb.x; bv[kk][1]=tb.y; bv[kk][2]=tb.z; bv[kk][3]=tb.w;
            }
            #pragma unroll
            for (int kk = 0; kk < 4; ++kk)
                #pragma unroll
                for (int ii = 0; ii < 4; ++ii)
                    #pragma unroll
                    for (int jj = 0; jj < 4; ++jj)
                        acc[ii][jj] = fmaf(av[kk][ii], bv[kk][jj], acc[ii][jj]);
        }
    }
    float rci[4], rcj[4];
    #pragma unroll
    for (int ii = 0; ii < 4; ++ii) rci[ii] = cnorm[i0 + tx*4 + ii];
    #pragma unroll
    for (int jj = 0; jj < 4; ++jj) rcj[jj] = clnorm[j0 + ty*4 + jj];
    #pragma unroll
    for (int ii = 0; ii < 4; ++ii)
        #pragma unroll
        for (int jj = 0; jj < 4; ++jj)
            M[(size_t)(i0 + tx*4 + ii) * N + (j0 + ty*4 + jj)] = acc[ii][jj] / (rci[ii] * rcj[jj]);
}

// ---------- K2: per-row max + argmax (first-index tie-break) of M ----------
__global__ __launch_bounds__(256) void k_rowstat(const float* __restrict__ M,
                                                 float* __restrict__ rowmax,
                                                 int* __restrict__ rowarg) {
    __shared__ float sv[256];
    __shared__ int   sa[256];
    int i = blockIdx.x, tid = threadIdx.x;
    float bv = -INFINITY; int ba = 0;
    for (int j = tid; j < N; j += 256) {
        float v = M[(size_t)i * N + j];
        if (v > bv || (v == bv && j < ba)) { bv = v; ba = j; }
    }
    sv[tid] = bv; sa[tid] = ba;
    __syncthreads();
    for (int s = 128; s > 0; s >>= 1) {
        if (tid < s) {
            float v = sv[tid + s]; int a = sa[tid + s];
            if (v > sv[tid] || (v == sv[tid] && a < sa[tid])) { sv[tid] = v; sa[tid] = a; }
        }
        __syncthreads();
    }
    if (tid == 0) { rowmax[i] = sv[0]; rowarg[i] = sa[0]; }
}

// ---------- K3: centers -> bf16 MFMA B-fragments (fragment-linear) ----------
__global__ __launch_bounds__(64) void k_cenfrag(const float* __restrict__ centers,
                                                unsigned short* __restrict__ cenB) {
    int f = blockIdx.x;                 // nt*16 + kt
    int nt = f >> 4, kt = f & 15;
    int lane = threadIdx.x;
    int r = lane & 15, g = lane >> 4;
    const float* src = centers + (size_t)(nt * 16 + r) * C + kt * 32 + g * 4;
    float4 lo = *(const float4*)src;
    float4 hi = *(const float4*)(src + 16);
    union { unsigned short us[8]; uint4 q; } u;
    u.us[0]=f2bf(lo.x); u.us[1]=f2bf(lo.y); u.us[2]=f2bf(lo.z); u.us[3]=f2bf(lo.w);
    u.us[4]=f2bf(hi.x); u.us[5]=f2bf(hi.y); u.us[6]=f2bf(hi.z); u.us[7]=f2bf(hi.w);
    *(uint4*)(cenB + ((size_t)f * 64 + lane) * 8) = u.q;
}

// ---------- K4: FUSED — MFMA logits in registers -> max -> candidates -> exact refine -> idx ----------
__global__ __launch_bounds__(256, 2) void k_fused(const float* __restrict__ x,
                                                  const unsigned short* __restrict__ cenB,
                                                  const float* __restrict__ gumbel,
                                                  const float* __restrict__ centers,
                                                  int* __restrict__ idxb) {
    __shared__ float xs[C * 20];                 // [k][px] fp32, stride 20 (40 KB)
    __shared__ unsigned int pmax[16];
    __shared__ unsigned long long pixkey[16];
    __shared__ unsigned int candlist[CAP];
    __shared__ int candcount;

    int tid = threadIdx.x;
    int lane = tid & 63, w = tid >> 6;
    int r = lane & 15, g = lane >> 4;

    // block -> pixel tile, swizzled so consecutive tiles share an XCD
    int tile = (int)((blockIdx.x >> 3) | ((blockIdx.x & 7) << 8));
    int p0 = tile << 4;
    int b = p0 >> 12, hw0 = p0 & (HW - 1);

    if (tid < 16) { pmax[tid] = 0u; pixkey[tid] = 0ull; }
    if (tid == 0) candcount = 0;

    // ---- stage x tile: 512 k-rows x 16 px fp32, coalesced 64B per row ----
    const float* xb = x + (size_t)b * C * HW + hw0;
    #pragma unroll
    for (int kk = 0; kk < 8; ++kk) {
        int k = kk * 64 + (tid >> 2);
        int q = (tid & 3) << 2;
        float4 v = *(const float4*)(xb + (size_t)k * HW + q);
        *(float4*)&xs[k * 20 + q] = v;
    }
    __syncthreads();

    // ---- build A fragments (16 px x 512 k bf16) in registers ----
    s16x8 a[16];
    #pragma unroll
    for (int kt = 0; kt < 16; ++kt) {
        int kb = kt * 32 + g * 4;
        s16x8 t;
        #pragma unroll
        for (int e = 0; e < 4; ++e) {
            t[e]     = (short)f2bf(xs[(kb + e) * 20 + r]);
            t[4 + e] = (short)f2bf(xs[(kb + 16 + e) * 20 + r]);
        }
        a[kt] = t;
    }

    // ---- MFMA over this wave's 256 n; keep logits+gumbel in registers ----
    float keep[64];
    const float* grow = gumbel + ((size_t)b * N + r) * HW + hw0 + g * 4;
    #pragma unroll
    for (int nt = 0; nt < 16; ++nt) {
        int ntg = (w << 4) + nt;
        float4 gv = *(const float4*)(grow + (size_t)ntg * 16 * HW);
        f32x4 acc = {0.f, 0.f, 0.f, 0.f};
        #pragma unroll
        for (int kt = 0; kt < 16; ++kt) {
            s16x8 bf = *(const s16x8*)(cenB + (((size_t)ntg * 16 + kt) * 64 + lane) * 8);
            acc = __builtin_amdgcn_mfma_f32_16x16x32_bf16(a[kt], bf, acc, 0, 0, 0);
        }
        keep[nt * 4 + 0] = acc[0] + gv.x;
        keep[nt * 4 + 1] = acc[1] + gv.y;
        keep[nt * 4 + 2] = acc[2] + gv.z;
        keep[nt * 4 + 3] = acc[3] + gv.w;
    }

    // ---- per-pixel approx max: in-lane over nt, shfl over r, LDS over waves ----
    float m4[4];
    #pragma unroll
    for (int j = 0; j < 4; ++j) {
        float m = keep[j];
        #pragma unroll
        for (int nt = 1; nt < 16; ++nt) m = fmaxf(m, keep[nt * 4 + j]);
        m4[j] = m;
    }
    #pragma unroll
    for (int s2 = 1; s2 < 16; s2 <<= 1)
        #pragma unroll
        for (int j = 0; j < 4; ++j) m4[j] = fmaxf(m4[j], __shfl_xor(m4[j], s2, 64));
    if (r == 0) {
        #pragma unroll
        for (int j = 0; j < 4; ++j) atomicMax(&pmax[g * 4 + j], mono(m4[j]));
    }
    __syncthreads();

    // ---- candidate scan (margin covers bf16 MFMA error) ----
    float thr[4];
    #pragma unroll
    for (int j = 0; j < 4; ++j) thr[j] = unmono(pmax[g * 4 + j]) - MARGIN;
    #pragma unroll
    for (int nt = 0; nt < 16; ++nt)
        #pragma unroll
        for (int j = 0; j < 4; ++j)
            if (keep[nt * 4 + j] >= thr[j]) {
                int n = (((w << 4) + nt) << 4) + r;
                int pos = atomicAdd(&candcount, 1);
                if (pos < CAP) candlist[pos] = (unsigned int)n | ((unsigned int)(g * 4 + j) << 12);
            }
    __syncthreads();

    // ---- exact fp32 refine (x from LDS, centers from L2), winner via u64 atomicMax ----
    int cc = candcount; if (cc > CAP) cc = CAP;
    for (int t = w; t < cc; t += 4) {
        unsigned int e = candlist[t];
        int n = (int)(e & 1023u), pl = (int)(e >> 12);
        float s = 0.f;
        #pragma unroll
        for (int mm = 0; mm < 8; ++mm) {
            int k = lane + (mm << 6);
            s = fmaf(xs[k * 20 + pl], centers[(size_t)n * C + k], s);
        }
        #pragma unroll
        for (int s2 = 1; s2 < 64; s2 <<= 1) s += __shfl_xor(s, s2, 64);
        float val = s + gumbel[((size_t)b * N + n) * HW + hw0 + pl];
        if (lane == 0) {
            unsigned long long key = ((unsigned long long)mono(val) << 32) | (unsigned int)(1023 - n);
            atomicMax(&pixkey[pl], key);
        }
    }
    __syncthreads();
    if (tid < 16) idxb[p0 + tid] = 1023 - (int)(unsigned int)(pixkey[tid] & 0xFFFFFFFFull);
}

// ---------- K5: preds (as float) + per-block loss partial sums ----------
__global__ __launch_bounds__(256) void k_preds(const int* __restrict__ idxb,
                                               const float* __restrict__ rowmax,
                                               const int* __restrict__ rowarg,
                                               float* __restrict__ preds_out,
                                               float* __restrict__ partial) {
    __shared__ float sv[256];
    int gid = blockIdx.x * 256 + threadIdx.x;
    int i = idxb[gid];
    preds_out[gid] = (float)rowarg[i];
    sv[threadIdx.x] = rowmax[i];
    __syncthreads();
    for (int s = 128; s > 0; s >>= 1) {
        if (threadIdx.x < s) sv[threadIdx.x] += sv[threadIdx.x + s];
        __syncthreads();
    }
    if (threadIdx.x == 0) partial[blockIdx.x] = sv[0];
}

// ---------- K6: gather rows of src by idx and write transposed (coalesced) ----------
__global__ __launch_bounds__(256) void k_gather(const float* __restrict__ src, int ncols,
                                                const int* __restrict__ idx,
                                                float* __restrict__ dst) {
    __shared__ float rows[64][65];
    int tile = blockIdx.x;
    int col0 = blockIdx.y * 64;
    int tid = threadIdx.x;
    int lane = tid & 63, w = tid >> 6;
    int b = tile >> 6, hw0 = (tile & 63) << 6;
    #pragma unroll
    for (int r8 = 0; r8 < 16; ++r8) {
        int r = w * 16 + r8;
        int row = idx[tile * 64 + r];
        rows[r][lane] = src[(size_t)row * ncols + col0 + lane];
    }
    __syncthreads();
    #pragma unroll
    for (int jj = 0; jj < 16; ++jj) {
        int j = col0 + w * 16 + jj;
        dst[((size_t)b * ncols + j) * HW + hw0 + lane] = rows[lane][w * 16 + jj];
    }
}

// ---------- K7: finalize loss ----------
__global__ __launch_bounds__(128) void k_loss(const float* __restrict__ partial,
                                              float* __restrict__ out) {
    __shared__ float sv[128];
    sv[threadIdx.x] = partial[threadIdx.x];
    __syncthreads();
    for (int s = 64; s > 0; s >>= 1) {
        if (threadIdx.x < s) sv[threadIdx.x] += sv[threadIdx.x + s];
        __syncthreads();
    }
    if (threadIdx.x == 0) out[0] = -(sv[0] / 32768.0f);
}

extern "C" void kernel_launch(void* const* d_in, const int* in_sizes, int n_in,
                              void* d_out, int out_size, void* d_ws, size_t ws_size,
                              hipStream_t stream) {
    const float* x        = (const float*)d_in[0];
    const float* centers  = (const float*)d_in[1];
    const float* clusters = (const float*)d_in[2];
    const float* gumbel   = (const float*)d_in[3];
    float* out = (float*)d_out;

    char* w = (char*)d_ws;
    int*   idxb    = (int*)w;                                  // 128 KB
    float* cnorm   = (float*)(w + 131072);                     // 4 KB
    float* clnorm  = cnorm + 1024;
    float* rowmax  = clnorm + 1024;
    int*   rowarg  = (int*)(rowmax + 1024);
    float* partial = (float*)(rowarg + 1024);
    float* M       = (float*)(w + 262144);                     // 4 MB
    unsigned short* cenB = (unsigned short*)(w + 4456448);     // 1 MB

    float* out_loss  = out;
    float* out_preds = out + 1;
    float* out_ip    = out + 1 + 32768;
    float* out_zq    = out + 1 + 32768 + (size_t)N * NPIX;

    k_norms  <<<2048, 64, 0, stream>>>(centers, clusters, cnorm, clnorm);
    k_gemmM  <<<dim3(16, 16), 256, 0, stream>>>(centers, clusters, cnorm, clnorm, M);
    k_rowstat<<<1024, 256, 0, stream>>>(M, rowmax, rowarg);
    k_cenfrag<<<1024, 64, 0, stream>>>(centers, cenB);
    k_fused  <<<2048, 256, 0, stream>>>(x, cenB, gumbel, centers, idxb);
    k_preds  <<<128, 256, 0, stream>>>(idxb, rowmax, rowarg, out_preds, partial);
    k_gather <<<dim3(512, 16), 256, 0, stream>>>(M, N, idxb, out_ip);
    k_gather <<<dim3(512, 8),  256, 0, stream>>>(centers, C, idxb, out_zq);
    k_loss   <<<1, 128, 0, stream>>>(partial, out_loss);
}